// Round 8
// baseline (2176.268 us; speedup 1.0000x reference)
//
#include <hip/hip_runtime.h>

static constexpr int B = 32, N = 2048, BN = B * N;

#define DEV static __device__ __forceinline__

typedef _Float16 half_t;
typedef __attribute__((ext_vector_type(8))) _Float16 half8;
typedef __attribute__((ext_vector_type(4))) float f32x4;

DEV float lk(float v) { return v >= 0.f ? v : 0.01f * v; }
DEV bool lexlt(float d1, int j1, float d2, int j2) {
    return d1 < d2 || (d1 == d2 && j1 < j2);
}

DEV unsigned int mono(float f) {
    unsigned int b = __float_as_uint(f);
    return (b & 0x80000000u) ? ~b : (b | 0x80000000u);
}
DEV int mbcnt64(unsigned long long m) {
    return __builtin_amdgcn_mbcnt_hi((unsigned)(m >> 32),
                                     __builtin_amdgcn_mbcnt_lo((unsigned)m, 0));
}
DEV float dist4(float4 a, float sa, float4 b) {
    float sb = fmaf(b.x, b.x, fmaf(b.y, b.y, fmaf(b.z, b.z, b.w * b.w)));
    float dt = fmaf(a.x, b.x, fmaf(a.y, b.y, fmaf(a.z, b.z, a.w * b.w)));
    return (sa + sb) - 2.f * dt;
}

// ---------------------------------------------------------------- build xx
__global__ __launch_bounds__(256) void k_build_xx(const float* __restrict__ x,
                                                  const float* __restrict__ pos,
                                                  float* __restrict__ xx) {
    int i = blockIdx.x * 256 + threadIdx.x;
    if (i < BN) {
        float4 v;
        v.x = x[i];
        v.y = pos[3 * i + 0];
        v.z = pos[3 * i + 1];
        v.w = pos[3 * i + 2];
        ((float4*)xx)[i] = v;
    }
}

// ------------------------------------------------- knn(F=4) + homophily + conv1 idx
__global__ __launch_bounds__(256) void k_knn4(const float* __restrict__ xx,
                                              int* __restrict__ c1idx,
                                              unsigned int* __restrict__ hpart) {
    int gw = (blockIdx.x * 256 + threadIdx.x) >> 6;  // global row id
    int lane = threadIdx.x & 63;
    int g = gw >> 11, i = gw & 2047;
    int lane_self = i & 63, t_self = i >> 6;
    const float4* base = ((const float4*)xx) + g * N;
    float4 xi = base[i];
    float si = fmaf(xi.x, xi.x, fmaf(xi.y, xi.y, fmaf(xi.z, xi.z, xi.w * xi.w)));

    unsigned int u[32];
    unsigned int e0 = 0, e1 = 0, e2 = 0, e3 = 0;
    unsigned int L[6];
#pragma unroll
    for (int s = 0; s < 6; s++) L[s] = 0xFFFFFFFFu;
#pragma unroll
    for (int t = 0; t < 32; t++) {
        float4 xj = base[lane + 64 * t];
        unsigned int uv = mono(dist4(xi, si, xj));
        u[t] = uv;
        e0 |= (xj.x == xi.x ? 1u : 0u) << t;
        e1 |= (xj.y == xi.y ? 1u : 0u) << t;
        e2 |= (xj.z == xi.z ? 1u : 0u) << t;
        e3 |= (xj.w == xi.w ? 1u : 0u) << t;
        unsigned int nv = uv;
#pragma unroll
        for (int s = 0; s < 6; s++) {
            unsigned int lo = min(L[s], nv);
            nv = max(L[s], nv);
            L[s] = lo;
        }
    }
    unsigned int uself = 0x80000000u;  // mono(0.0f)

    unsigned int vA = 0, vB = 0;
#pragma unroll 1
    for (int bit = 31; bit >= 0; --bit) {
        unsigned int cA = vA | (1u << bit);
        unsigned int cB = vB | (1u << bit);
        int cntA = 0, cntB = 0;
#pragma unroll
        for (int s = 0; s < 6; s++) {
            cntA += (int)__popcll(__ballot(L[s] < cA));
            cntB += (int)__popcll(__ballot(L[s] < cB));
        }
        cntA -= (uself < cA) ? 1 : 0;
        if (cntA < 50) vA = cA;
        if (cntB < 5) vB = cB;
    }
    if (__ballot(L[5] < vA) != 0ULL) {
        vA = 0;
#pragma unroll 1
        for (int bit = 31; bit >= 0; --bit) {
            unsigned int c = vA | (1u << bit);
            int cnt = 0;
#pragma unroll
            for (int t = 0; t < 32; t++) cnt += (int)__popcll(__ballot(u[t] < c));
            cnt -= (uself < c) ? 1 : 0;
            if (cnt < 50) vA = c;
        }
        vB = 0;
#pragma unroll 1
        for (int bit = 31; bit >= 0; --bit) {
            unsigned int c = vB | (1u << bit);
            int cnt = 0;
#pragma unroll
            for (int t = 0; t < 32; t++) cnt += (int)__popcll(__ballot(u[t] < c));
            if (cnt < 5) vB = c;
        }
    }

    unsigned int rawA = 0, eqAm = 0, rawB = 0, eqBm = 0;
#pragma unroll
    for (int t = 0; t < 32; t++) {
        rawA |= (u[t] < vA ? 1u : 0u) << t;
        eqAm |= (u[t] == vA ? 1u : 0u) << t;
        rawB |= (u[t] < vB ? 1u : 0u) << t;
        eqBm |= (u[t] == vB ? 1u : 0u) << t;
    }
    unsigned int packA = (unsigned)__popc(rawA) | ((unsigned)__popc(eqAm) << 16);
    unsigned int packB = (unsigned)__popc(rawB) | ((unsigned)__popc(eqBm) << 16);
#pragma unroll
    for (int o = 1; o < 64; o <<= 1) {
        packA += __shfl_xor(packA, o);
        packB += __shfl_xor(packB, o);
    }
    int cltA = (int)(packA & 0xffffu) - ((uself < vA) ? 1 : 0);
    int ceqA = (int)(packA >> 16) - ((uself == vA) ? 1 : 0);
    int cltB = (int)(packB & 0xffffu);
    int ceqB = (int)(packB >> 16);

    int neededA = 50 - cltA;
    bool allEqA = (ceqA == neededA);
    unsigned int selAm = rawA, eqAs = eqAm;
    if (lane == lane_self) {
        selAm &= ~(1u << t_self);
        eqAs &= ~(1u << t_self);
    }
    unsigned int hm = allEqA ? (selAm | eqAs) : selAm;
    int c0 = __popc(e0 & hm), c1 = __popc(e1 & hm);
    int c2 = __popc(e2 & hm), c3 = __popc(e3 & hm);
    if (!allEqA) {
        unsigned int em = eqAs;
        for (int r = 0; r < neededA; r++) {
            int mt = __ffs(em) - 1;
            int mj = (mt >= 0) ? (lane + 64 * mt) : 0x7fffffff;
            int bm = mj;
#pragma unroll
            for (int o = 1; o < 64; o <<= 1) bm = min(bm, __shfl_xor(bm, o));
            if (mj == bm && mt >= 0) {
                em &= ~(1u << mt);
                c0 += (e0 >> mt) & 1; c1 += (e1 >> mt) & 1;
                c2 += (e2 >> mt) & 1; c3 += (e3 >> mt) & 1;
            }
        }
    }
    unsigned int pc = (unsigned)c0 | ((unsigned)c1 << 8) | ((unsigned)c2 << 16) | ((unsigned)c3 << 24);
#pragma unroll
    for (int o = 1; o < 64; o <<= 1) pc += __shfl_xor(pc, o);
    if (lane == 0) hpart[gw] = pc;

    int neededB = 5 - cltB;
    bool allEqB = (ceqB == neededB);
    unsigned int selBm = allEqB ? (rawB | eqBm) : rawB;
    int base_slot = 0;
#pragma unroll 4
    for (int t = 0; t < 32; t++) {
        bool take = (selBm >> t) & 1;
        unsigned long long m = __ballot(take);
        if (take) c1idx[gw * 5 + base_slot + mbcnt64(m)] = lane + 64 * t;
        base_slot += (int)__popcll(m);
    }
    if (!allEqB) {
        unsigned int em = eqBm;
        for (int r = 0; r < neededB; r++) {
            int mt = __ffs(em) - 1;
            int mj = (mt >= 0) ? (lane + 64 * mt) : 0x7fffffff;
            int bm = mj;
#pragma unroll
            for (int o = 1; o < 64; o <<= 1) bm = min(bm, __shfl_xor(bm, o));
            if (mj == bm && mt >= 0) {
                em &= ~(1u << mt);
                c1idx[gw * 5 + base_slot + r] = bm;
            }
        }
    }
}

// ------------------------------------- fp32 -> fp16 hi/lo split + squared norms
__global__ __launch_bounds__(256) void k_split(const float* __restrict__ X,
                                               half_t* __restrict__ Xh,
                                               half_t* __restrict__ Xl,
                                               float* __restrict__ s) {
    int row = (blockIdx.x * 256 + threadIdx.x) >> 6;
    int lane = threadIdx.x & 63;
    float x = X[(size_t)row * 64 + lane];
    half_t h = (half_t)x;
    half_t l = (half_t)(x - (float)h);
    Xh[(size_t)row * 64 + lane] = h;
    Xl[(size_t)row * 64 + lane] = l;
    float ss = x * x;
#pragma unroll
    for (int o = 1; o < 64; o <<= 1) ss += __shfl_xor(ss, o);
    if (lane == 0) s[row] = ss;
}

// ----------------------------------------- node-level layer-1 split: p = x(Wa-Wb)+b1, q = x Wb
template <int F, int C>
__global__ __launch_bounds__(256, 4) void k_pq(const float* __restrict__ X,
                                               const float* __restrict__ w1,
                                               const float* __restrict__ b1,
                                               float* __restrict__ p,
                                               float* __restrict__ q) {
    constexpr int FS = F + 4;
    __shared__ __align__(16) float Xs[64 * FS];
    __shared__ __align__(16) float Ws[64 * FS];
    int nbase = blockIdx.x * 64;
    int cchunk = blockIdx.y;
    int tx = threadIdx.x & 15, ty = threadIdx.x >> 4;
    for (int idx = threadIdx.x; idx < 64 * (F / 4); idx += 256) {
        int r = idx / (F / 4), fq = idx % (F / 4);
        float4 v = ((const float4*)(X + (size_t)(nbase + r) * F))[fq];
        *(float4*)&Xs[r * FS + fq * 4] = v;
    }
    for (int idx = threadIdx.x; idx < 64 * F; idx += 256) {
        int f = idx >> 6, cl = idx & 63;
        int ccg = cchunk * 64 + cl;
        float v;
        if (ccg < C) v = w1[f * C + ccg] - w1[(F + f) * C + ccg];
        else         v = w1[(F + f) * C + (ccg - C)];
        Ws[cl * FS + f] = v;
    }
    __syncthreads();
    float acc[4][4];
#pragma unroll
    for (int a = 0; a < 4; a++)
#pragma unroll
        for (int b = 0; b < 4; b++) acc[a][b] = 0.f;
#pragma unroll 2
    for (int fs = 0; fs < F / 4; fs++) {
        float4 xv[4], wv[4];
#pragma unroll
        for (int a = 0; a < 4; a++) xv[a] = *(const float4*)&Xs[(ty + 16 * a) * FS + fs * 4];
#pragma unroll
        for (int b = 0; b < 4; b++) wv[b] = *(const float4*)&Ws[(tx + 16 * b) * FS + fs * 4];
#pragma unroll
        for (int a = 0; a < 4; a++)
#pragma unroll
            for (int b = 0; b < 4; b++) {
                acc[a][b] = fmaf(xv[a].x, wv[b].x, acc[a][b]);
                acc[a][b] = fmaf(xv[a].y, wv[b].y, acc[a][b]);
                acc[a][b] = fmaf(xv[a].z, wv[b].z, acc[a][b]);
                acc[a][b] = fmaf(xv[a].w, wv[b].w, acc[a][b]);
            }
    }
#pragma unroll
    for (int a = 0; a < 4; a++) {
        int n = nbase + ty + 16 * a;
#pragma unroll
        for (int b = 0; b < 4; b++) {
            int ccg = cchunk * 64 + tx + 16 * b;
            if (ccg < C) p[(size_t)n * C + ccg] = acc[a][b] + b1[ccg];
            else         q[(size_t)n * C + (ccg - C)] = acc[a][b];
        }
    }
}

// --------------------------------- per-edge layer 2: h2 = leaky(h1 @ w2 + b2), sum over k=5
template <int C1>
__global__ __launch_bounds__(256, 4) void k_edge(const float* __restrict__ p,
                                                 const float* __restrict__ q,
                                                 const int* __restrict__ cidx,
                                                 const float* __restrict__ w2,
                                                 const float* __restrict__ b2,
                                                 float* __restrict__ Xout) {
    __shared__ __align__(16) float h1[80 * 68];
    __shared__ __align__(16) float w2T[64 * 68];
    int nb = blockIdx.x * 16;
    int gb = (nb >> 11) << 11;  // graph base node
    int tx = threadIdx.x & 15, ty = threadIdx.x >> 4;
    float acc[5][4];
#pragma unroll
    for (int m = 0; m < 5; m++)
#pragma unroll
        for (int n = 0; n < 4; n++) acc[m][n] = 0.f;
#pragma unroll 1
    for (int half = 0; half < C1 / 64; half++) {
        __syncthreads();
        for (int idx = threadIdx.x; idx < 64 * 64; idx += 256) {
            int l = idx >> 6, c = idx & 63;
            w2T[c * 68 + l] = w2[(half * 64 + l) * 64 + c];
        }
        for (int idx = threadIdx.x; idx < 80 * 16; idx += 256) {
            int e = idx >> 4, fq = idx & 15;
            int node = nb + e / 5, kk = e - 5 * (e / 5);
            int j = cidx[node * 5 + kk];
            float4 pv = ((const float4*)(p + (size_t)node * C1 + half * 64))[fq];
            float4 qv = ((const float4*)(q + (size_t)(gb + j) * C1 + half * 64))[fq];
            float4 hv;
            hv.x = lk(pv.x + qv.x); hv.y = lk(pv.y + qv.y);
            hv.z = lk(pv.z + qv.z); hv.w = lk(pv.w + qv.w);
            *(float4*)&h1[e * 68 + fq * 4] = hv;
        }
        __syncthreads();
#pragma unroll 1
        for (int ls = 0; ls < 16; ls++) {
            float4 hv[5], wf[4];
#pragma unroll
            for (int m = 0; m < 5; m++) hv[m] = *(const float4*)&h1[(ty + 16 * m) * 68 + ls * 4];
#pragma unroll
            for (int n = 0; n < 4; n++) wf[n] = *(const float4*)&w2T[(tx + 16 * n) * 68 + ls * 4];
#pragma unroll
            for (int m = 0; m < 5; m++)
#pragma unroll
                for (int n = 0; n < 4; n++) {
                    acc[m][n] = fmaf(hv[m].x, wf[n].x, acc[m][n]);
                    acc[m][n] = fmaf(hv[m].y, wf[n].y, acc[m][n]);
                    acc[m][n] = fmaf(hv[m].z, wf[n].z, acc[m][n]);
                    acc[m][n] = fmaf(hv[m].w, wf[n].w, acc[m][n]);
                }
        }
    }
    float b2r[4];
#pragma unroll
    for (int n = 0; n < 4; n++) b2r[n] = b2[tx + 16 * n];
    __syncthreads();  // all h1 reads done; reuse h1 region for h2
    float* h2 = h1;
#pragma unroll
    for (int m = 0; m < 5; m++)
#pragma unroll
        for (int n = 0; n < 4; n++)
            h2[(ty + 16 * m) * 68 + (tx + 16 * n)] = lk(acc[m][n] + b2r[n]);
    __syncthreads();
#pragma unroll
    for (int rr = 0; rr < 4; rr++) {
        int idx = threadIdx.x + 256 * rr;
        int node = idx >> 6, c = idx & 63;
        float sum = 0.f;
#pragma unroll
        for (int kk = 0; kk < 5; kk++) sum += h2[(node * 5 + kk) * 68 + c];
        Xout[(size_t)(nb + node) * 64 + c] = sum;
    }
}

// --------------------------------------------- knn over F=64 features, top-5 (self incl.)
// MFMA split-fp16 Gram, 4 independent accumulator chains (hh/hl/lh/ll).
// No launch_bounds min-waves: avoid unified VGPR/AGPR budget squeeze -> no scratch spill.
__global__ __launch_bounds__(256) void k_knn64(const half_t* __restrict__ Xh,
                                               const half_t* __restrict__ Xl,
                                               const float* __restrict__ s,
                                               int* __restrict__ cidx) {
    __shared__ __align__(16) half_t XiH[64 * 72], XiL[64 * 72];
    __shared__ __align__(16) half_t XjH[64 * 72], XjL[64 * 72];
    __shared__ float sI[64], sJ[64];
    int g = blockIdx.x, it = blockIdx.y;
    int gbase = g * 2048, ibase = it * 64;
    int lane = threadIdx.x & 63, wave = threadIdx.x >> 6;
    int m = lane & 15, quad = lane >> 4;

    // stage Xi (hi/lo) once
    for (int idx = threadIdx.x; idx < 512; idx += 256) {
        int r = idx >> 3, c = idx & 7;
        *(half8*)&XiH[r * 72 + c * 8] = *(const half8*)(Xh + (size_t)(gbase + ibase + r) * 64 + c * 8);
        *(half8*)&XiL[r * 72 + c * 8] = *(const half8*)(Xl + (size_t)(gbase + ibase + r) * 64 + c * 8);
    }
    if (threadIdx.x < 64) sI[threadIdx.x] = s[gbase + ibase + threadIdx.x];
    __syncthreads();

    // per-wave A fragments (constant over the whole j loop)
    int arow = (wave * 16 + m) * 72 + quad * 8;
    half8 Ah0 = *(const half8*)&XiH[arow];
    half8 Ah1 = *(const half8*)&XiH[arow + 32];
    half8 Al0 = *(const half8*)&XiL[arow];
    half8 Al1 = *(const half8*)&XiL[arow + 32];
    float si_r[4];
#pragma unroll
    for (int reg = 0; reg < 4; reg++) si_r[reg] = sI[wave * 16 + quad * 4 + reg];

    float t5v[4][5];
    int t5j[4][5];
#pragma unroll
    for (int a = 0; a < 4; a++)
#pragma unroll
        for (int ss = 0; ss < 5; ss++) { t5v[a][ss] = __builtin_inff(); t5j[a][ss] = 0x7fffffff; }

#pragma unroll 1
    for (int jt = 0; jt < 32; jt++) {
        __syncthreads();
        for (int idx = threadIdx.x; idx < 512; idx += 256) {
            int r = idx >> 3, c = idx & 7;
            *(half8*)&XjH[r * 72 + c * 8] = *(const half8*)(Xh + (size_t)(gbase + jt * 64 + r) * 64 + c * 8);
            *(half8*)&XjL[r * 72 + c * 8] = *(const half8*)(Xl + (size_t)(gbase + jt * 64 + r) * 64 + c * 8);
        }
        if (threadIdx.x < 64) sJ[threadIdx.x] = s[gbase + jt * 64 + threadIdx.x];
        __syncthreads();
#pragma unroll
        for (int sub = 0; sub < 4; sub++) {
            int brow = (sub * 16 + m) * 72 + quad * 8;
            half8 Bh0 = *(const half8*)&XjH[brow];
            half8 Bh1 = *(const half8*)&XjH[brow + 32];
            half8 Bl0 = *(const half8*)&XjL[brow];
            half8 Bl1 = *(const half8*)&XjL[brow + 32];
            f32x4 ahh = {0.f, 0.f, 0.f, 0.f};
            f32x4 ahl = {0.f, 0.f, 0.f, 0.f};
            f32x4 alh = {0.f, 0.f, 0.f, 0.f};
            f32x4 all = {0.f, 0.f, 0.f, 0.f};
            ahh = __builtin_amdgcn_mfma_f32_16x16x32_f16(Ah0, Bh0, ahh, 0, 0, 0);
            ahl = __builtin_amdgcn_mfma_f32_16x16x32_f16(Ah0, Bl0, ahl, 0, 0, 0);
            alh = __builtin_amdgcn_mfma_f32_16x16x32_f16(Al0, Bh0, alh, 0, 0, 0);
            all = __builtin_amdgcn_mfma_f32_16x16x32_f16(Al0, Bl0, all, 0, 0, 0);
            ahh = __builtin_amdgcn_mfma_f32_16x16x32_f16(Ah1, Bh1, ahh, 0, 0, 0);
            ahl = __builtin_amdgcn_mfma_f32_16x16x32_f16(Ah1, Bl1, ahl, 0, 0, 0);
            alh = __builtin_amdgcn_mfma_f32_16x16x32_f16(Al1, Bh1, alh, 0, 0, 0);
            all = __builtin_amdgcn_mfma_f32_16x16x32_f16(Al1, Bl1, all, 0, 0, 0);
            float sjv = sJ[sub * 16 + m];
            int jv = jt * 64 + sub * 16 + m;
#pragma unroll
            for (int reg = 0; reg < 4; reg++) {
                float dot = ((all[reg] + alh[reg]) + ahl[reg]) + ahh[reg];
                float dv = (si_r[reg] + sjv) - 2.f * dot;
                if (lexlt(dv, jv, t5v[reg][4], t5j[reg][4])) {
                    t5v[reg][4] = dv; t5j[reg][4] = jv;
#pragma unroll
                    for (int ss = 4; ss >= 1; ss--)
                        if (lexlt(t5v[reg][ss], t5j[reg][ss], t5v[reg][ss - 1], t5j[reg][ss - 1])) {
                            float tv = t5v[reg][ss]; t5v[reg][ss] = t5v[reg][ss - 1]; t5v[reg][ss - 1] = tv;
                            int tj = t5j[reg][ss]; t5j[reg][ss] = t5j[reg][ss - 1]; t5j[reg][ss - 1] = tj;
                        }
                }
            }
        }
    }

    // merge: 4 phases (one per reg); 16 rows/phase, 16 lanes x 5 cands each.
    float* candd = (float*)XiH;   // 16*80 floats = 5.1 KB (fits XiH region)
    int* candj = (int*)XiL;
#pragma unroll 1
    for (int reg = 0; reg < 4; reg++) {
        __syncthreads();
        int rowc = wave * 4 + quad;
#pragma unroll
        for (int ss = 0; ss < 5; ss++) {
            candd[rowc * 80 + m * 5 + ss] = t5v[reg][ss];
            candj[rowc * 80 + m * 5 + ss] = t5j[reg][ss];
        }
        __syncthreads();
        if (threadIdx.x < 16) {
            int t = threadIdx.x;
            float fv[5];
            int fj[5];
#pragma unroll
            for (int ss = 0; ss < 5; ss++) { fv[ss] = __builtin_inff(); fj[ss] = 0x7fffffff; }
#pragma unroll 1
            for (int c = 0; c < 80; c++) {
                float dv = candd[t * 80 + c];
                int jv = candj[t * 80 + c];
                if (lexlt(dv, jv, fv[4], fj[4])) {
                    fv[4] = dv; fj[4] = jv;
#pragma unroll
                    for (int ss = 4; ss >= 1; ss--)
                        if (lexlt(fv[ss], fj[ss], fv[ss - 1], fj[ss - 1])) {
                            float tv = fv[ss]; fv[ss] = fv[ss - 1]; fv[ss - 1] = tv;
                            int tj = fj[ss]; fj[ss] = fj[ss - 1]; fj[ss - 1] = tj;
                        }
                }
            }
            int local = (t >> 2) * 16 + (t & 3) * 4 + reg;
#pragma unroll
            for (int ss = 0; ss < 5; ss++)
                cidx[(size_t)(gbase + ibase + local) * 5 + ss] = fj[ss];
        }
    }
}

// ------------------------- lin1 layer1 + leaky + mean-pool accumulate
__global__ __launch_bounds__(256, 3) void k_lin1(const float* __restrict__ xx,
                                                 const float* __restrict__ x1,
                                                 const float* __restrict__ x2,
                                                 const float* __restrict__ x3,
                                                 const float* __restrict__ w1,
                                                 const float* __restrict__ b1,
                                                 float* __restrict__ Hpart) {
    __shared__ __align__(16) float ft[64 * 100];
    __shared__ __align__(16) float wT[64 * 100];
    int cch = blockIdx.x, g = blockIdx.y, z = blockIdx.z;
    int gbase = g * 2048;
    int tx = threadIdx.x & 15, ty = threadIdx.x >> 4;
    float accp[4][4][4];  // [nt][rm][ca]
#pragma unroll
    for (int nt = 0; nt < 4; nt++)
#pragma unroll
        for (int rm = 0; rm < 4; rm++)
#pragma unroll
            for (int ca = 0; ca < 4; ca++) accp[nt][rm][ca] = 0.f;
#pragma unroll 1
    for (int half = 0; half < 2; half++) {
        int FH = half ? 96 : 100;
        __syncthreads();
        for (int idx = threadIdx.x; idx < 64 * 100; idx += 256) {
            int f = idx >> 6, cl = idx & 63;
            if (f < FH) wT[cl * 100 + f] = w1[(half * 100 + f) * 512 + cch * 64 + cl];
        }
        int NF4 = half ? 24 : 25;
#pragma unroll 1
        for (int nt = 0; nt < 4; nt++) {
            int n0 = (z * 4 + nt) * 64;
            __syncthreads();
            for (int idx = threadIdx.x; idx < 64 * NF4; idx += 256) {
                int r = idx / NF4, fq = idx - r * NF4;
                int node = gbase + n0 + r;
                float4 v;
                if (half == 0) {
                    if (fq == 0)      v = ((const float4*)(xx + (size_t)node * 4))[0];
                    else if (fq < 17) v = ((const float4*)(x1 + (size_t)node * 64))[fq - 1];
                    else              v = ((const float4*)(x2 + (size_t)node * 64))[fq - 17];
                } else {
                    if (fq < 8)       v = ((const float4*)(x2 + (size_t)node * 64))[fq + 8];
                    else              v = ((const float4*)(x3 + (size_t)node * 64))[fq - 8];
                }
                *(float4*)&ft[r * 100 + fq * 4] = v;
            }
            __syncthreads();
            int FSN = NF4;
#pragma unroll 2
            for (int fs = 0; fs < FSN; fs++) {
                float4 fv[4], wv[4];
#pragma unroll
                for (int rm = 0; rm < 4; rm++) fv[rm] = *(const float4*)&ft[(ty + 16 * rm) * 100 + fs * 4];
#pragma unroll
                for (int ca = 0; ca < 4; ca++) wv[ca] = *(const float4*)&wT[(tx + 16 * ca) * 100 + fs * 4];
#pragma unroll
                for (int rm = 0; rm < 4; rm++)
#pragma unroll
                    for (int ca = 0; ca < 4; ca++) {
                        accp[nt][rm][ca] = fmaf(fv[rm].x, wv[ca].x, accp[nt][rm][ca]);
                        accp[nt][rm][ca] = fmaf(fv[rm].y, wv[ca].y, accp[nt][rm][ca]);
                        accp[nt][rm][ca] = fmaf(fv[rm].z, wv[ca].z, accp[nt][rm][ca]);
                        accp[nt][rm][ca] = fmaf(fv[rm].w, wv[ca].w, accp[nt][rm][ca]);
                    }
            }
        }
    }
    float b1r[4];
#pragma unroll
    for (int ca = 0; ca < 4; ca++) b1r[ca] = b1[cch * 64 + tx + 16 * ca];
    float psum[4] = {0.f, 0.f, 0.f, 0.f};
#pragma unroll
    for (int nt = 0; nt < 4; nt++)
#pragma unroll
        for (int rm = 0; rm < 4; rm++)
#pragma unroll
            for (int ca = 0; ca < 4; ca++) psum[ca] += lk(accp[nt][rm][ca] + b1r[ca]);
    __syncthreads();
    float* red = ft;  // 16 x 64
#pragma unroll
    for (int ca = 0; ca < 4; ca++) red[ty * 64 + tx + 16 * ca] = psum[ca];
    __syncthreads();
    if (threadIdx.x < 64) {
        float tot = 0.f;
#pragma unroll
        for (int t = 0; t < 16; t++) tot += red[t * 64 + threadIdx.x];
        Hpart[((size_t)z * 32 + g) * 512 + cch * 64 + threadIdx.x] = tot;
    }
}

// ------------------------------------------------------------- per-graph head
__global__ __launch_bounds__(256) void k_final(const float* __restrict__ Hpart,
                                               const unsigned int* __restrict__ hpart,
                                               const float* __restrict__ l1w2,
                                               const float* __restrict__ l1b2,
                                               const float* __restrict__ mw1,
                                               const float* __restrict__ mb1,
                                               const float* __restrict__ mw2,
                                               const float* __restrict__ mb2,
                                               float* __restrict__ out) {
    __shared__ float Hb[512];
    __shared__ float z[260];
    __shared__ float y[256];
    __shared__ unsigned int hsum[4];
    int g = blockIdx.x, t = threadIdx.x;
    if (t < 4) hsum[t] = 0;
    __syncthreads();
    unsigned int s0 = 0, s1 = 0, s2 = 0, s3 = 0;
#pragma unroll
    for (int r = 0; r < 8; r++) {
        unsigned int v = hpart[g * 2048 + t + 256 * r];
        s0 += v & 0xffu; s1 += (v >> 8) & 0xffu;
        s2 += (v >> 16) & 0xffu; s3 += (v >> 24) & 0xffu;
    }
    atomicAdd(&hsum[0], s0); atomicAdd(&hsum[1], s1);
    atomicAdd(&hsum[2], s2); atomicAdd(&hsum[3], s3);
#pragma unroll
    for (int half = 0; half < 2; half++) {
        int c = t + 256 * half;
        float v = 0.f;
#pragma unroll
        for (int zz = 0; zz < 8; zz++) v += Hpart[((size_t)zz * 32 + g) * 512 + c];
        Hb[c] = v * (1.f / 2048.f);
    }
    __syncthreads();
    float acc = l1b2[t];
    for (int f = 0; f < 512; f++) acc = fmaf(Hb[f], l1w2[f * 256 + t], acc);
    z[t] = lk(acc);
    if (t < 4) z[256 + t] = lk((float)hsum[t] * (1.f / (2048.f * 50.f)));
    __syncthreads();
    float acc2 = mb1[t];
    for (int f = 0; f < 260; f++) acc2 = fmaf(z[f], mw1[f * 256 + t], acc2);
    y[t] = lk(acc2);
    __syncthreads();
    if (t < 3) {
        float a = mb2[t];
        for (int c = 0; c < 256; c++) a = fmaf(y[c], mw2[c * 3 + t], a);
        out[g * 3 + t] = a;
    }
}

// ------------------------------------------------------------------ launcher
extern "C" void kernel_launch(void* const* d_in, const int* in_sizes, int n_in,
                              void* d_out, int out_size, void* d_ws, size_t ws_size,
                              hipStream_t stream) {
    (void)in_sizes; (void)n_in; (void)out_size; (void)ws_size;
    const float* x    = (const float*)d_in[0];
    const float* pos  = (const float*)d_in[1];
    const float* c1w1 = (const float*)d_in[3];
    const float* c1b1 = (const float*)d_in[4];
    const float* c1w2 = (const float*)d_in[5];
    const float* c1b2 = (const float*)d_in[6];
    const float* c2w1 = (const float*)d_in[7];
    const float* c2b1 = (const float*)d_in[8];
    const float* c2w2 = (const float*)d_in[9];
    const float* c2b2 = (const float*)d_in[10];
    const float* l1w1 = (const float*)d_in[11];
    const float* l1b1 = (const float*)d_in[12];
    const float* l1w2 = (const float*)d_in[13];
    const float* l1b2 = (const float*)d_in[14];
    const float* mw1  = (const float*)d_in[15];
    const float* mb1  = (const float*)d_in[16];
    const float* mw2  = (const float*)d_in[17];
    const float* mb2  = (const float*)d_in[18];
    float* out = (float*)d_out;

    char* w = (char*)d_ws;
    auto alloc = [&](size_t bytes) -> void* {
        void* r = (void*)w;
        w += (bytes + 255) & ~(size_t)255;
        return r;
    };
    float* xx   = (float*)alloc((size_t)BN * 4 * 4);
    float* pbuf = (float*)alloc((size_t)BN * 128 * 4);
    float* qbuf = (float*)alloc((size_t)BN * 128 * 4);
    float* x1   = (float*)alloc((size_t)BN * 64 * 4);
    float* x2   = (float*)alloc((size_t)BN * 64 * 4);
    float* x3   = (float*)alloc((size_t)BN * 64 * 4);
    float* sbuf = (float*)alloc((size_t)BN * 4);
    half_t* xh  = (half_t*)alloc((size_t)BN * 64 * 2);
    half_t* xl  = (half_t*)alloc((size_t)BN * 64 * 2);
    int* c1i    = (int*)alloc((size_t)BN * 5 * 4);
    int* c2i    = (int*)alloc((size_t)BN * 5 * 4);
    int* c3i    = (int*)alloc((size_t)BN * 5 * 4);
    unsigned int* hpart = (unsigned int*)alloc((size_t)BN * 4);
    float* Hpart = (float*)alloc((size_t)8 * 32 * 512 * 4);

    k_build_xx<<<BN / 256, 256, 0, stream>>>(x, pos, xx);
    k_knn4<<<BN / 4, 256, 0, stream>>>(xx, c1i, hpart);
    // conv1
    k_pq<4, 64><<<dim3(BN / 64, 2), 256, 0, stream>>>(xx, c1w1, c1b1, pbuf, qbuf);
    k_edge<64><<<BN / 16, 256, 0, stream>>>(pbuf, qbuf, c1i, c1w2, c1b2, x1);
    // conv2
    k_split<<<BN / 4, 256, 0, stream>>>(x1, xh, xl, sbuf);
    k_knn64<<<dim3(32, 32), 256, 0, stream>>>(xh, xl, sbuf, c2i);
    k_pq<64, 128><<<dim3(BN / 64, 4), 256, 0, stream>>>(x1, c2w1, c2b1, pbuf, qbuf);
    k_edge<128><<<BN / 16, 256, 0, stream>>>(pbuf, qbuf, c2i, c2w2, c2b2, x2);
    // conv3 (shared conv2 weights)
    k_split<<<BN / 4, 256, 0, stream>>>(x2, xh, xl, sbuf);
    k_knn64<<<dim3(32, 32), 256, 0, stream>>>(xh, xl, sbuf, c3i);
    k_pq<64, 128><<<dim3(BN / 64, 4), 256, 0, stream>>>(x2, c2w1, c2b1, pbuf, qbuf);
    k_edge<128><<<BN / 16, 256, 0, stream>>>(pbuf, qbuf, c3i, c2w2, c2b2, x3);
    // lin1 layer1 + pool (8-way split), then head
    k_lin1<<<dim3(8, 32, 8), 256, 0, stream>>>(xx, x1, x2, x3, l1w1, l1b1, Hpart);
    k_final<<<32, 256, 0, stream>>>(Hpart, hpart, l1w2, l1b2, mw1, mb1, mw2, mb2, out);
}

// Round 9
// 1822.313 us; speedup vs baseline: 1.1942x; 1.1942x over previous
//
#include <hip/hip_runtime.h>

static constexpr int B = 32, N = 2048, BN = B * N;

#define DEV static __device__ __forceinline__

typedef _Float16 half_t;
typedef __attribute__((ext_vector_type(8))) _Float16 half8;
typedef __attribute__((ext_vector_type(4))) float f32x4;

DEV float lk(float v) { return v >= 0.f ? v : 0.01f * v; }
DEV bool lexlt(float d1, int j1, float d2, int j2) {
    return d1 < d2 || (d1 == d2 && j1 < j2);
}

DEV unsigned int mono(float f) {
    unsigned int b = __float_as_uint(f);
    return (b & 0x80000000u) ? ~b : (b | 0x80000000u);
}
DEV int mbcnt64(unsigned long long m) {
    return __builtin_amdgcn_mbcnt_hi((unsigned)(m >> 32),
                                     __builtin_amdgcn_mbcnt_lo((unsigned)m, 0));
}
DEV float dist4(float4 a, float sa, float4 b) {
    float sb = fmaf(b.x, b.x, fmaf(b.y, b.y, fmaf(b.z, b.z, b.w * b.w)));
    float dt = fmaf(a.x, b.x, fmaf(a.y, b.y, fmaf(a.z, b.z, a.w * b.w)));
    return (sa + sb) - 2.f * dt;
}

// ---------------------------------------------------------------- build xx
__global__ __launch_bounds__(256) void k_build_xx(const float* __restrict__ x,
                                                  const float* __restrict__ pos,
                                                  float* __restrict__ xx) {
    int i = blockIdx.x * 256 + threadIdx.x;
    if (i < BN) {
        float4 v;
        v.x = x[i];
        v.y = pos[3 * i + 0];
        v.z = pos[3 * i + 1];
        v.w = pos[3 * i + 2];
        ((float4*)xx)[i] = v;
    }
}

// ------------------------------------------------- knn(F=4) + homophily + conv1 idx
__global__ __launch_bounds__(256) void k_knn4(const float* __restrict__ xx,
                                              int* __restrict__ c1idx,
                                              unsigned int* __restrict__ hpart) {
    int gw = (blockIdx.x * 256 + threadIdx.x) >> 6;  // global row id
    int lane = threadIdx.x & 63;
    int g = gw >> 11, i = gw & 2047;
    int lane_self = i & 63, t_self = i >> 6;
    const float4* base = ((const float4*)xx) + g * N;
    float4 xi = base[i];
    float si = fmaf(xi.x, xi.x, fmaf(xi.y, xi.y, fmaf(xi.z, xi.z, xi.w * xi.w)));

    unsigned int u[32];
    unsigned int e0 = 0, e1 = 0, e2 = 0, e3 = 0;
    unsigned int L[6];
#pragma unroll
    for (int s = 0; s < 6; s++) L[s] = 0xFFFFFFFFu;
#pragma unroll
    for (int t = 0; t < 32; t++) {
        float4 xj = base[lane + 64 * t];
        unsigned int uv = mono(dist4(xi, si, xj));
        u[t] = uv;
        e0 |= (xj.x == xi.x ? 1u : 0u) << t;
        e1 |= (xj.y == xi.y ? 1u : 0u) << t;
        e2 |= (xj.z == xi.z ? 1u : 0u) << t;
        e3 |= (xj.w == xi.w ? 1u : 0u) << t;
        unsigned int nv = uv;
#pragma unroll
        for (int s = 0; s < 6; s++) {
            unsigned int lo = min(L[s], nv);
            nv = max(L[s], nv);
            L[s] = lo;
        }
    }
    unsigned int uself = 0x80000000u;  // mono(0.0f)

    unsigned int vA = 0, vB = 0;
#pragma unroll 1
    for (int bit = 31; bit >= 0; --bit) {
        unsigned int cA = vA | (1u << bit);
        unsigned int cB = vB | (1u << bit);
        int cntA = 0, cntB = 0;
#pragma unroll
        for (int s = 0; s < 6; s++) {
            cntA += (int)__popcll(__ballot(L[s] < cA));
            cntB += (int)__popcll(__ballot(L[s] < cB));
        }
        cntA -= (uself < cA) ? 1 : 0;
        if (cntA < 50) vA = cA;
        if (cntB < 5) vB = cB;
    }
    if (__ballot(L[5] < vA) != 0ULL) {
        vA = 0;
#pragma unroll 1
        for (int bit = 31; bit >= 0; --bit) {
            unsigned int c = vA | (1u << bit);
            int cnt = 0;
#pragma unroll
            for (int t = 0; t < 32; t++) cnt += (int)__popcll(__ballot(u[t] < c));
            cnt -= (uself < c) ? 1 : 0;
            if (cnt < 50) vA = c;
        }
        vB = 0;
#pragma unroll 1
        for (int bit = 31; bit >= 0; --bit) {
            unsigned int c = vB | (1u << bit);
            int cnt = 0;
#pragma unroll
            for (int t = 0; t < 32; t++) cnt += (int)__popcll(__ballot(u[t] < c));
            if (cnt < 5) vB = c;
        }
    }

    unsigned int rawA = 0, eqAm = 0, rawB = 0, eqBm = 0;
#pragma unroll
    for (int t = 0; t < 32; t++) {
        rawA |= (u[t] < vA ? 1u : 0u) << t;
        eqAm |= (u[t] == vA ? 1u : 0u) << t;
        rawB |= (u[t] < vB ? 1u : 0u) << t;
        eqBm |= (u[t] == vB ? 1u : 0u) << t;
    }
    unsigned int packA = (unsigned)__popc(rawA) | ((unsigned)__popc(eqAm) << 16);
    unsigned int packB = (unsigned)__popc(rawB) | ((unsigned)__popc(eqBm) << 16);
#pragma unroll
    for (int o = 1; o < 64; o <<= 1) {
        packA += __shfl_xor(packA, o);
        packB += __shfl_xor(packB, o);
    }
    int cltA = (int)(packA & 0xffffu) - ((uself < vA) ? 1 : 0);
    int ceqA = (int)(packA >> 16) - ((uself == vA) ? 1 : 0);
    int cltB = (int)(packB & 0xffffu);
    int ceqB = (int)(packB >> 16);

    int neededA = 50 - cltA;
    bool allEqA = (ceqA == neededA);
    unsigned int selAm = rawA, eqAs = eqAm;
    if (lane == lane_self) {
        selAm &= ~(1u << t_self);
        eqAs &= ~(1u << t_self);
    }
    unsigned int hm = allEqA ? (selAm | eqAs) : selAm;
    int c0 = __popc(e0 & hm), c1 = __popc(e1 & hm);
    int c2 = __popc(e2 & hm), c3 = __popc(e3 & hm);
    if (!allEqA) {
        unsigned int em = eqAs;
        for (int r = 0; r < neededA; r++) {
            int mt = __ffs(em) - 1;
            int mj = (mt >= 0) ? (lane + 64 * mt) : 0x7fffffff;
            int bm = mj;
#pragma unroll
            for (int o = 1; o < 64; o <<= 1) bm = min(bm, __shfl_xor(bm, o));
            if (mj == bm && mt >= 0) {
                em &= ~(1u << mt);
                c0 += (e0 >> mt) & 1; c1 += (e1 >> mt) & 1;
                c2 += (e2 >> mt) & 1; c3 += (e3 >> mt) & 1;
            }
        }
    }
    unsigned int pc = (unsigned)c0 | ((unsigned)c1 << 8) | ((unsigned)c2 << 16) | ((unsigned)c3 << 24);
#pragma unroll
    for (int o = 1; o < 64; o <<= 1) pc += __shfl_xor(pc, o);
    if (lane == 0) hpart[gw] = pc;

    int neededB = 5 - cltB;
    bool allEqB = (ceqB == neededB);
    unsigned int selBm = allEqB ? (rawB | eqBm) : rawB;
    int base_slot = 0;
#pragma unroll 4
    for (int t = 0; t < 32; t++) {
        bool take = (selBm >> t) & 1;
        unsigned long long m = __ballot(take);
        if (take) c1idx[gw * 5 + base_slot + mbcnt64(m)] = lane + 64 * t;
        base_slot += (int)__popcll(m);
    }
    if (!allEqB) {
        unsigned int em = eqBm;
        for (int r = 0; r < neededB; r++) {
            int mt = __ffs(em) - 1;
            int mj = (mt >= 0) ? (lane + 64 * mt) : 0x7fffffff;
            int bm = mj;
#pragma unroll
            for (int o = 1; o < 64; o <<= 1) bm = min(bm, __shfl_xor(bm, o));
            if (mj == bm && mt >= 0) {
                em &= ~(1u << mt);
                c1idx[gw * 5 + base_slot + r] = bm;
            }
        }
    }
}

// ------------------------------------- fp32 -> fp16 hi/lo split + squared norms
__global__ __launch_bounds__(256) void k_split(const float* __restrict__ X,
                                               half_t* __restrict__ Xh,
                                               half_t* __restrict__ Xl,
                                               float* __restrict__ s) {
    int row = (blockIdx.x * 256 + threadIdx.x) >> 6;
    int lane = threadIdx.x & 63;
    float x = X[(size_t)row * 64 + lane];
    half_t h = (half_t)x;
    half_t l = (half_t)(x - (float)h);
    Xh[(size_t)row * 64 + lane] = h;
    Xl[(size_t)row * 64 + lane] = l;
    float ss = x * x;
#pragma unroll
    for (int o = 1; o < 64; o <<= 1) ss += __shfl_xor(ss, o);
    if (lane == 0) s[row] = ss;
}

// ----------------------------------------- node-level layer-1 split: p = x(Wa-Wb)+b1, q = x Wb
template <int F, int C>
__global__ __launch_bounds__(256, 4) void k_pq(const float* __restrict__ X,
                                               const float* __restrict__ w1,
                                               const float* __restrict__ b1,
                                               float* __restrict__ p,
                                               float* __restrict__ q) {
    constexpr int FS = F + 4;
    __shared__ __align__(16) float Xs[64 * FS];
    __shared__ __align__(16) float Ws[64 * FS];
    int nbase = blockIdx.x * 64;
    int cchunk = blockIdx.y;
    int tx = threadIdx.x & 15, ty = threadIdx.x >> 4;
    for (int idx = threadIdx.x; idx < 64 * (F / 4); idx += 256) {
        int r = idx / (F / 4), fq = idx % (F / 4);
        float4 v = ((const float4*)(X + (size_t)(nbase + r) * F))[fq];
        *(float4*)&Xs[r * FS + fq * 4] = v;
    }
    for (int idx = threadIdx.x; idx < 64 * F; idx += 256) {
        int f = idx >> 6, cl = idx & 63;
        int ccg = cchunk * 64 + cl;
        float v;
        if (ccg < C) v = w1[f * C + ccg] - w1[(F + f) * C + ccg];
        else         v = w1[(F + f) * C + (ccg - C)];
        Ws[cl * FS + f] = v;
    }
    __syncthreads();
    float acc[4][4];
#pragma unroll
    for (int a = 0; a < 4; a++)
#pragma unroll
        for (int b = 0; b < 4; b++) acc[a][b] = 0.f;
#pragma unroll 2
    for (int fs = 0; fs < F / 4; fs++) {
        float4 xv[4], wv[4];
#pragma unroll
        for (int a = 0; a < 4; a++) xv[a] = *(const float4*)&Xs[(ty + 16 * a) * FS + fs * 4];
#pragma unroll
        for (int b = 0; b < 4; b++) wv[b] = *(const float4*)&Ws[(tx + 16 * b) * FS + fs * 4];
#pragma unroll
        for (int a = 0; a < 4; a++)
#pragma unroll
            for (int b = 0; b < 4; b++) {
                acc[a][b] = fmaf(xv[a].x, wv[b].x, acc[a][b]);
                acc[a][b] = fmaf(xv[a].y, wv[b].y, acc[a][b]);
                acc[a][b] = fmaf(xv[a].z, wv[b].z, acc[a][b]);
                acc[a][b] = fmaf(xv[a].w, wv[b].w, acc[a][b]);
            }
    }
#pragma unroll
    for (int a = 0; a < 4; a++) {
        int n = nbase + ty + 16 * a;
#pragma unroll
        for (int b = 0; b < 4; b++) {
            int ccg = cchunk * 64 + tx + 16 * b;
            if (ccg < C) p[(size_t)n * C + ccg] = acc[a][b] + b1[ccg];
            else         q[(size_t)n * C + (ccg - C)] = acc[a][b];
        }
    }
}

// --------------------------------- per-edge layer 2: h2 = leaky(h1 @ w2 + b2), sum over k=5
template <int C1>
__global__ __launch_bounds__(256, 4) void k_edge(const float* __restrict__ p,
                                                 const float* __restrict__ q,
                                                 const int* __restrict__ cidx,
                                                 const float* __restrict__ w2,
                                                 const float* __restrict__ b2,
                                                 float* __restrict__ Xout) {
    __shared__ __align__(16) float h1[80 * 68];
    __shared__ __align__(16) float w2T[64 * 68];
    int nb = blockIdx.x * 16;
    int gb = (nb >> 11) << 11;  // graph base node
    int tx = threadIdx.x & 15, ty = threadIdx.x >> 4;
    float acc[5][4];
#pragma unroll
    for (int m = 0; m < 5; m++)
#pragma unroll
        for (int n = 0; n < 4; n++) acc[m][n] = 0.f;
#pragma unroll 1
    for (int half = 0; half < C1 / 64; half++) {
        __syncthreads();
        for (int idx = threadIdx.x; idx < 64 * 64; idx += 256) {
            int l = idx >> 6, c = idx & 63;
            w2T[c * 68 + l] = w2[(half * 64 + l) * 64 + c];
        }
        for (int idx = threadIdx.x; idx < 80 * 16; idx += 256) {
            int e = idx >> 4, fq = idx & 15;
            int node = nb + e / 5, kk = e - 5 * (e / 5);
            int j = cidx[node * 5 + kk];
            float4 pv = ((const float4*)(p + (size_t)node * C1 + half * 64))[fq];
            float4 qv = ((const float4*)(q + (size_t)(gb + j) * C1 + half * 64))[fq];
            float4 hv;
            hv.x = lk(pv.x + qv.x); hv.y = lk(pv.y + qv.y);
            hv.z = lk(pv.z + qv.z); hv.w = lk(pv.w + qv.w);
            *(float4*)&h1[e * 68 + fq * 4] = hv;
        }
        __syncthreads();
#pragma unroll 1
        for (int ls = 0; ls < 16; ls++) {
            float4 hv[5], wf[4];
#pragma unroll
            for (int m = 0; m < 5; m++) hv[m] = *(const float4*)&h1[(ty + 16 * m) * 68 + ls * 4];
#pragma unroll
            for (int n = 0; n < 4; n++) wf[n] = *(const float4*)&w2T[(tx + 16 * n) * 68 + ls * 4];
#pragma unroll
            for (int m = 0; m < 5; m++)
#pragma unroll
                for (int n = 0; n < 4; n++) {
                    acc[m][n] = fmaf(hv[m].x, wf[n].x, acc[m][n]);
                    acc[m][n] = fmaf(hv[m].y, wf[n].y, acc[m][n]);
                    acc[m][n] = fmaf(hv[m].z, wf[n].z, acc[m][n]);
                    acc[m][n] = fmaf(hv[m].w, wf[n].w, acc[m][n]);
                }
        }
    }
    float b2r[4];
#pragma unroll
    for (int n = 0; n < 4; n++) b2r[n] = b2[tx + 16 * n];
    __syncthreads();  // all h1 reads done; reuse h1 region for h2
    float* h2 = h1;
#pragma unroll
    for (int m = 0; m < 5; m++)
#pragma unroll
        for (int n = 0; n < 4; n++)
            h2[(ty + 16 * m) * 68 + (tx + 16 * n)] = lk(acc[m][n] + b2r[n]);
    __syncthreads();
#pragma unroll
    for (int rr = 0; rr < 4; rr++) {
        int idx = threadIdx.x + 256 * rr;
        int node = idx >> 6, c = idx & 63;
        float sum = 0.f;
#pragma unroll
        for (int kk = 0; kk < 5; kk++) sum += h2[(node * 5 + kk) * 68 + c];
        Xout[(size_t)(nb + node) * 64 + c] = sum;
    }
}

// --------------------------------------------- knn over F=64 features, top-5 (self incl.)
// MFMA split-fp16 Gram + exact-safe threshold filter:
// theta[reg] = cross-lane min (16 m-lanes share the same 4 i-rows) of per-lane
// 5th-best >= global 5th-best, so dv > theta can never be global top-5.
__global__ __launch_bounds__(256) void k_knn64(const half_t* __restrict__ Xh,
                                               const half_t* __restrict__ Xl,
                                               const float* __restrict__ s,
                                               int* __restrict__ cidx) {
    __shared__ __align__(16) char smem[37376];
    half_t* XiH = (half_t*)smem;
    half_t* XiL = (half_t*)(smem + 9216);
    half_t* XjH = (half_t*)(smem + 18432);
    half_t* XjL = (half_t*)(smem + 27648);
    float* sI = (float*)(smem + 36864);
    float* sJ = (float*)(smem + 37120);
    int g = blockIdx.x, it = blockIdx.y;
    int gbase = g * 2048, ibase = it * 64;
    int lane = threadIdx.x & 63, wave = threadIdx.x >> 6;
    int m = lane & 15, quad = lane >> 4;

    // stage Xi (hi/lo) once
    for (int idx = threadIdx.x; idx < 512; idx += 256) {
        int r = idx >> 3, c = idx & 7;
        *(half8*)&XiH[r * 72 + c * 8] = *(const half8*)(Xh + (size_t)(gbase + ibase + r) * 64 + c * 8);
        *(half8*)&XiL[r * 72 + c * 8] = *(const half8*)(Xl + (size_t)(gbase + ibase + r) * 64 + c * 8);
    }
    if (threadIdx.x < 64) sI[threadIdx.x] = s[gbase + ibase + threadIdx.x];
    __syncthreads();

    // per-wave A fragments (constant over the whole j loop)
    int arow = (wave * 16 + m) * 72 + quad * 8;
    half8 Ah0 = *(const half8*)&XiH[arow];
    half8 Ah1 = *(const half8*)&XiH[arow + 32];
    half8 Al0 = *(const half8*)&XiL[arow];
    half8 Al1 = *(const half8*)&XiL[arow + 32];
    float si_r[4];
#pragma unroll
    for (int reg = 0; reg < 4; reg++) si_r[reg] = sI[wave * 16 + quad * 4 + reg];

    float t5v[4][5];
    int t5j[4][5];
    float thv[4];
#pragma unroll
    for (int a = 0; a < 4; a++) {
        thv[a] = __builtin_inff();
#pragma unroll
        for (int ss = 0; ss < 5; ss++) { t5v[a][ss] = __builtin_inff(); t5j[a][ss] = 0x7fffffff; }
    }

#pragma unroll 1
    for (int jt = 0; jt < 32; jt++) {
        __syncthreads();
        for (int idx = threadIdx.x; idx < 512; idx += 256) {
            int r = idx >> 3, c = idx & 7;
            *(half8*)&XjH[r * 72 + c * 8] = *(const half8*)(Xh + (size_t)(gbase + jt * 64 + r) * 64 + c * 8);
            *(half8*)&XjL[r * 72 + c * 8] = *(const half8*)(Xl + (size_t)(gbase + jt * 64 + r) * 64 + c * 8);
        }
        if (threadIdx.x < 64) sJ[threadIdx.x] = s[gbase + jt * 64 + threadIdx.x];
        __syncthreads();
        // refresh safe thresholds (stale-high = safe)
#pragma unroll
        for (int reg = 0; reg < 4; reg++) {
            float th = t5v[reg][4];
            th = fminf(th, __shfl_xor(th, 1));
            th = fminf(th, __shfl_xor(th, 2));
            th = fminf(th, __shfl_xor(th, 4));
            th = fminf(th, __shfl_xor(th, 8));
            thv[reg] = th;
        }
#pragma unroll
        for (int sub = 0; sub < 4; sub++) {
            int brow = (sub * 16 + m) * 72 + quad * 8;
            half8 Bh0 = *(const half8*)&XjH[brow];
            half8 Bh1 = *(const half8*)&XjH[brow + 32];
            half8 Bl0 = *(const half8*)&XjL[brow];
            half8 Bl1 = *(const half8*)&XjL[brow + 32];
            f32x4 ahh = {0.f, 0.f, 0.f, 0.f};
            f32x4 ahl = {0.f, 0.f, 0.f, 0.f};
            f32x4 alh = {0.f, 0.f, 0.f, 0.f};
            f32x4 all = {0.f, 0.f, 0.f, 0.f};
            ahh = __builtin_amdgcn_mfma_f32_16x16x32_f16(Ah0, Bh0, ahh, 0, 0, 0);
            ahl = __builtin_amdgcn_mfma_f32_16x16x32_f16(Ah0, Bl0, ahl, 0, 0, 0);
            alh = __builtin_amdgcn_mfma_f32_16x16x32_f16(Al0, Bh0, alh, 0, 0, 0);
            all = __builtin_amdgcn_mfma_f32_16x16x32_f16(Al0, Bl0, all, 0, 0, 0);
            ahh = __builtin_amdgcn_mfma_f32_16x16x32_f16(Ah1, Bh1, ahh, 0, 0, 0);
            ahl = __builtin_amdgcn_mfma_f32_16x16x32_f16(Ah1, Bl1, ahl, 0, 0, 0);
            alh = __builtin_amdgcn_mfma_f32_16x16x32_f16(Al1, Bh1, alh, 0, 0, 0);
            all = __builtin_amdgcn_mfma_f32_16x16x32_f16(Al1, Bl1, all, 0, 0, 0);
            float sjv = sJ[sub * 16 + m];
            int jv = jt * 64 + sub * 16 + m;
#pragma unroll
            for (int reg = 0; reg < 4; reg++) {
                float dot = ((all[reg] + alh[reg]) + ahl[reg]) + ahh[reg];
                float dv = (si_r[reg] + sjv) - 2.f * dot;
                if (dv <= thv[reg]) {  // safe filter: dv > theta cannot be global top-5
                    if (lexlt(dv, jv, t5v[reg][4], t5j[reg][4])) {
                        t5v[reg][4] = dv; t5j[reg][4] = jv;
#pragma unroll
                        for (int ss = 4; ss >= 1; ss--)
                            if (lexlt(t5v[reg][ss], t5j[reg][ss], t5v[reg][ss - 1], t5j[reg][ss - 1])) {
                                float tv = t5v[reg][ss]; t5v[reg][ss] = t5v[reg][ss - 1]; t5v[reg][ss - 1] = tv;
                                int tj = t5j[reg][ss]; t5j[reg][ss] = t5j[reg][ss - 1]; t5j[reg][ss - 1] = tj;
                            }
                    }
                }
            }
        }
    }

    // single-phase merge: 64 rows x 80 candidates (ushort idx), reusing staging LDS
    float* candd = (float*)smem;                          // 64*80*4 = 20480 B
    unsigned short* candj = (unsigned short*)(smem + 20480);  // 64*80*2 = 10240 B
    __syncthreads();
    int rowbase = wave * 16 + quad * 4;
#pragma unroll
    for (int reg = 0; reg < 4; reg++)
#pragma unroll
        for (int ss = 0; ss < 5; ss++) {
            candd[(rowbase + reg) * 80 + m * 5 + ss] = t5v[reg][ss];
            candj[(rowbase + reg) * 80 + m * 5 + ss] = (unsigned short)t5j[reg][ss];
        }
    __syncthreads();
    if (threadIdx.x < 64) {
        int row = threadIdx.x;
        float fv[5];
        int fj[5];
#pragma unroll
        for (int ss = 0; ss < 5; ss++) { fv[ss] = __builtin_inff(); fj[ss] = 0x7fffffff; }
#pragma unroll 1
        for (int c = 0; c < 80; c++) {
            float dv = candd[row * 80 + c];
            int jv = (int)candj[row * 80 + c];
            if (lexlt(dv, jv, fv[4], fj[4])) {
                fv[4] = dv; fj[4] = jv;
#pragma unroll
                for (int ss = 4; ss >= 1; ss--)
                    if (lexlt(fv[ss], fj[ss], fv[ss - 1], fj[ss - 1])) {
                        float tv = fv[ss]; fv[ss] = fv[ss - 1]; fv[ss - 1] = tv;
                        int tj = fj[ss]; fj[ss] = fj[ss - 1]; fj[ss - 1] = tj;
                    }
            }
        }
#pragma unroll
        for (int ss = 0; ss < 5; ss++)
            cidx[(size_t)(gbase + ibase + row) * 5 + ss] = fj[ss];
    }
}

// ------------------------- lin1 layer1 + leaky + mean-pool accumulate
__global__ __launch_bounds__(256, 3) void k_lin1(const float* __restrict__ xx,
                                                 const float* __restrict__ x1,
                                                 const float* __restrict__ x2,
                                                 const float* __restrict__ x3,
                                                 const float* __restrict__ w1,
                                                 const float* __restrict__ b1,
                                                 float* __restrict__ Hpart) {
    __shared__ __align__(16) float ft[64 * 100];
    __shared__ __align__(16) float wT[64 * 100];
    int cch = blockIdx.x, g = blockIdx.y, z = blockIdx.z;
    int gbase = g * 2048;
    int tx = threadIdx.x & 15, ty = threadIdx.x >> 4;
    float accp[4][4][4];  // [nt][rm][ca]
#pragma unroll
    for (int nt = 0; nt < 4; nt++)
#pragma unroll
        for (int rm = 0; rm < 4; rm++)
#pragma unroll
            for (int ca = 0; ca < 4; ca++) accp[nt][rm][ca] = 0.f;
#pragma unroll 1
    for (int half = 0; half < 2; half++) {
        int FH = half ? 96 : 100;
        __syncthreads();
        for (int idx = threadIdx.x; idx < 64 * 100; idx += 256) {
            int f = idx >> 6, cl = idx & 63;
            if (f < FH) wT[cl * 100 + f] = w1[(half * 100 + f) * 512 + cch * 64 + cl];
        }
        int NF4 = half ? 24 : 25;
#pragma unroll 1
        for (int nt = 0; nt < 4; nt++) {
            int n0 = (z * 4 + nt) * 64;
            __syncthreads();
            for (int idx = threadIdx.x; idx < 64 * NF4; idx += 256) {
                int r = idx / NF4, fq = idx - r * NF4;
                int node = gbase + n0 + r;
                float4 v;
                if (half == 0) {
                    if (fq == 0)      v = ((const float4*)(xx + (size_t)node * 4))[0];
                    else if (fq < 17) v = ((const float4*)(x1 + (size_t)node * 64))[fq - 1];
                    else              v = ((const float4*)(x2 + (size_t)node * 64))[fq - 17];
                } else {
                    if (fq < 8)       v = ((const float4*)(x2 + (size_t)node * 64))[fq + 8];
                    else              v = ((const float4*)(x3 + (size_t)node * 64))[fq - 8];
                }
                *(float4*)&ft[r * 100 + fq * 4] = v;
            }
            __syncthreads();
            int FSN = NF4;
#pragma unroll 2
            for (int fs = 0; fs < FSN; fs++) {
                float4 fv[4], wv[4];
#pragma unroll
                for (int rm = 0; rm < 4; rm++) fv[rm] = *(const float4*)&ft[(ty + 16 * rm) * 100 + fs * 4];
#pragma unroll
                for (int ca = 0; ca < 4; ca++) wv[ca] = *(const float4*)&wT[(tx + 16 * ca) * 100 + fs * 4];
#pragma unroll
                for (int rm = 0; rm < 4; rm++)
#pragma unroll
                    for (int ca = 0; ca < 4; ca++) {
                        accp[nt][rm][ca] = fmaf(fv[rm].x, wv[ca].x, accp[nt][rm][ca]);
                        accp[nt][rm][ca] = fmaf(fv[rm].y, wv[ca].y, accp[nt][rm][ca]);
                        accp[nt][rm][ca] = fmaf(fv[rm].z, wv[ca].z, accp[nt][rm][ca]);
                        accp[nt][rm][ca] = fmaf(fv[rm].w, wv[ca].w, accp[nt][rm][ca]);
                    }
            }
        }
    }
    float b1r[4];
#pragma unroll
    for (int ca = 0; ca < 4; ca++) b1r[ca] = b1[cch * 64 + tx + 16 * ca];
    float psum[4] = {0.f, 0.f, 0.f, 0.f};
#pragma unroll
    for (int nt = 0; nt < 4; nt++)
#pragma unroll
        for (int rm = 0; rm < 4; rm++)
#pragma unroll
            for (int ca = 0; ca < 4; ca++) psum[ca] += lk(accp[nt][rm][ca] + b1r[ca]);
    __syncthreads();
    float* red = ft;  // 16 x 64
#pragma unroll
    for (int ca = 0; ca < 4; ca++) red[ty * 64 + tx + 16 * ca] = psum[ca];
    __syncthreads();
    if (threadIdx.x < 64) {
        float tot = 0.f;
#pragma unroll
        for (int t = 0; t < 16; t++) tot += red[t * 64 + threadIdx.x];
        Hpart[((size_t)z * 32 + g) * 512 + cch * 64 + threadIdx.x] = tot;
    }
}

// ------------------------------------------------------------- per-graph head
__global__ __launch_bounds__(256) void k_final(const float* __restrict__ Hpart,
                                               const unsigned int* __restrict__ hpart,
                                               const float* __restrict__ l1w2,
                                               const float* __restrict__ l1b2,
                                               const float* __restrict__ mw1,
                                               const float* __restrict__ mb1,
                                               const float* __restrict__ mw2,
                                               const float* __restrict__ mb2,
                                               float* __restrict__ out) {
    __shared__ float Hb[512];
    __shared__ float z[260];
    __shared__ float y[256];
    __shared__ unsigned int hsum[4];
    int g = blockIdx.x, t = threadIdx.x;
    if (t < 4) hsum[t] = 0;
    __syncthreads();
    unsigned int s0 = 0, s1 = 0, s2 = 0, s3 = 0;
#pragma unroll
    for (int r = 0; r < 8; r++) {
        unsigned int v = hpart[g * 2048 + t + 256 * r];
        s0 += v & 0xffu; s1 += (v >> 8) & 0xffu;
        s2 += (v >> 16) & 0xffu; s3 += (v >> 24) & 0xffu;
    }
    atomicAdd(&hsum[0], s0); atomicAdd(&hsum[1], s1);
    atomicAdd(&hsum[2], s2); atomicAdd(&hsum[3], s3);
#pragma unroll
    for (int half = 0; half < 2; half++) {
        int c = t + 256 * half;
        float v = 0.f;
#pragma unroll
        for (int zz = 0; zz < 8; zz++) v += Hpart[((size_t)zz * 32 + g) * 512 + c];
        Hb[c] = v * (1.f / 2048.f);
    }
    __syncthreads();
    float acc = l1b2[t];
    for (int f = 0; f < 512; f++) acc = fmaf(Hb[f], l1w2[f * 256 + t], acc);
    z[t] = lk(acc);
    if (t < 4) z[256 + t] = lk((float)hsum[t] * (1.f / (2048.f * 50.f)));
    __syncthreads();
    float acc2 = mb1[t];
    for (int f = 0; f < 260; f++) acc2 = fmaf(z[f], mw1[f * 256 + t], acc2);
    y[t] = lk(acc2);
    __syncthreads();
    if (t < 3) {
        float a = mb2[t];
        for (int c = 0; c < 256; c++) a = fmaf(y[c], mw2[c * 3 + t], a);
        out[g * 3 + t] = a;
    }
}

// ------------------------------------------------------------------ launcher
extern "C" void kernel_launch(void* const* d_in, const int* in_sizes, int n_in,
                              void* d_out, int out_size, void* d_ws, size_t ws_size,
                              hipStream_t stream) {
    (void)in_sizes; (void)n_in; (void)out_size; (void)ws_size;
    const float* x    = (const float*)d_in[0];
    const float* pos  = (const float*)d_in[1];
    const float* c1w1 = (const float*)d_in[3];
    const float* c1b1 = (const float*)d_in[4];
    const float* c1w2 = (const float*)d_in[5];
    const float* c1b2 = (const float*)d_in[6];
    const float* c2w1 = (const float*)d_in[7];
    const float* c2b1 = (const float*)d_in[8];
    const float* c2w2 = (const float*)d_in[9];
    const float* c2b2 = (const float*)d_in[10];
    const float* l1w1 = (const float*)d_in[11];
    const float* l1b1 = (const float*)d_in[12];
    const float* l1w2 = (const float*)d_in[13];
    const float* l1b2 = (const float*)d_in[14];
    const float* mw1  = (const float*)d_in[15];
    const float* mb1  = (const float*)d_in[16];
    const float* mw2  = (const float*)d_in[17];
    const float* mb2  = (const float*)d_in[18];
    float* out = (float*)d_out;

    char* w = (char*)d_ws;
    auto alloc = [&](size_t bytes) -> void* {
        void* r = (void*)w;
        w += (bytes + 255) & ~(size_t)255;
        return r;
    };
    float* xx   = (float*)alloc((size_t)BN * 4 * 4);
    float* pbuf = (float*)alloc((size_t)BN * 128 * 4);
    float* qbuf = (float*)alloc((size_t)BN * 128 * 4);
    float* x1   = (float*)alloc((size_t)BN * 64 * 4);
    float* x2   = (float*)alloc((size_t)BN * 64 * 4);
    float* x3   = (float*)alloc((size_t)BN * 64 * 4);
    float* sbuf = (float*)alloc((size_t)BN * 4);
    half_t* xh  = (half_t*)alloc((size_t)BN * 64 * 2);
    half_t* xl  = (half_t*)alloc((size_t)BN * 64 * 2);
    int* c1i    = (int*)alloc((size_t)BN * 5 * 4);
    int* c2i    = (int*)alloc((size_t)BN * 5 * 4);
    int* c3i    = (int*)alloc((size_t)BN * 5 * 4);
    unsigned int* hpart = (unsigned int*)alloc((size_t)BN * 4);
    float* Hpart = (float*)alloc((size_t)8 * 32 * 512 * 4);

    k_build_xx<<<BN / 256, 256, 0, stream>>>(x, pos, xx);
    k_knn4<<<BN / 4, 256, 0, stream>>>(xx, c1i, hpart);
    // conv1
    k_pq<4, 64><<<dim3(BN / 64, 2), 256, 0, stream>>>(xx, c1w1, c1b1, pbuf, qbuf);
    k_edge<64><<<BN / 16, 256, 0, stream>>>(pbuf, qbuf, c1i, c1w2, c1b2, x1);
    // conv2
    k_split<<<BN / 4, 256, 0, stream>>>(x1, xh, xl, sbuf);
    k_knn64<<<dim3(32, 32), 256, 0, stream>>>(xh, xl, sbuf, c2i);
    k_pq<64, 128><<<dim3(BN / 64, 4), 256, 0, stream>>>(x1, c2w1, c2b1, pbuf, qbuf);
    k_edge<128><<<BN / 16, 256, 0, stream>>>(pbuf, qbuf, c2i, c2w2, c2b2, x2);
    // conv3 (shared conv2 weights)
    k_split<<<BN / 4, 256, 0, stream>>>(x2, xh, xl, sbuf);
    k_knn64<<<dim3(32, 32), 256, 0, stream>>>(xh, xl, sbuf, c3i);
    k_pq<64, 128><<<dim3(BN / 64, 4), 256, 0, stream>>>(x2, c2w1, c2b1, pbuf, qbuf);
    k_edge<128><<<BN / 16, 256, 0, stream>>>(pbuf, qbuf, c3i, c2w2, c2b2, x3);
    // lin1 layer1 + pool (8-way split), then head
    k_lin1<<<dim3(8, 32, 8), 256, 0, stream>>>(xx, x1, x2, x3, l1w1, l1b1, Hpart);
    k_final<<<32, 256, 0, stream>>>(Hpart, hpart, l1w2, l1b2, mw1, mb1, mw2, mb2, out);
}